// Round 1
// baseline (807.479 us; speedup 1.0000x reference)
//
#include <hip/hip_runtime.h>
#include <math.h>

#define REFRACTORY 0.33f

// ---------------------------------------------------------------------------
// Kernel 0: detect whether rec_mask arrived as int32 (values 0/1 per dword)
// or as packed bool bytes (dword view of 4 bytes gives values > 1).
// Writes mode flag (1 = byte mode) to d_ws.
// ---------------------------------------------------------------------------
__global__ void detect_mask(const unsigned int* __restrict__ rm, int nwords,
                            int* __restrict__ flag) {
    __shared__ int s;
    if (threadIdx.x == 0) s = 0;
    __syncthreads();
    int found = 0;
    for (int i = threadIdx.x; i < nwords; i += blockDim.x)
        if (rm[i] > 1u) found = 1;
    if (found) atomicOr(&s, 1);
    __syncthreads();
    if (threadIdx.x == 0) *flag = s;
}

// ---------------------------------------------------------------------------
// Kernel 1: acc[n] = REFRACTORY*state[n] + biases[n]
// ---------------------------------------------------------------------------
__global__ void init_acc(const float* __restrict__ state,
                         const float* __restrict__ biases,
                         float* __restrict__ acc, int n) {
    int i = blockIdx.x * blockDim.x + threadIdx.x;
    int stride = gridDim.x * blockDim.x;
    for (; i < n; i += stride)
        acc[i] = REFRACTORY * state[i] + biases[i];
}

// ---------------------------------------------------------------------------
// Kernel 2: per-edge scatter-add. 4 edges per thread, vectorized loads.
// ---------------------------------------------------------------------------
__global__ void edge_scatter(const float* __restrict__ w,
                             const int* __restrict__ src,
                             const int* __restrict__ dst,
                             const unsigned char* __restrict__ rmb,
                             const int* __restrict__ input_idx,
                             const float* __restrict__ state,
                             const float* __restrict__ inp,
                             float* __restrict__ acc, int E,
                             const int* __restrict__ flag) {
    const int bytemode = *flag;  // uniform across grid
    int t = blockIdx.x * blockDim.x + threadIdx.x;
    int nq = E >> 2;
    if (t < nq) {
        float4 wv = ((const float4*)w)[t];
        int4 s4 = ((const int4*)src)[t];
        int4 d4 = ((const int4*)dst)[t];
        int4 i4 = ((const int4*)input_idx)[t];
        int m0, m1, m2, m3;
        if (bytemode) {
            unsigned int mm = ((const unsigned int*)rmb)[t];
            m0 = mm & 0xff; m1 = (mm >> 8) & 0xff;
            m2 = (mm >> 16) & 0xff; m3 = (mm >> 24) & 0xff;
        } else {
            int4 mi = ((const int4*)rmb)[t];
            m0 = mi.x; m1 = mi.y; m2 = mi.z; m3 = mi.w;
        }
        float v0 = m0 ? REFRACTORY * state[s4.x] : inp[i4.x];
        float v1 = m1 ? REFRACTORY * state[s4.y] : inp[i4.y];
        float v2 = m2 ? REFRACTORY * state[s4.z] : inp[i4.z];
        float v3 = m3 ? REFRACTORY * state[s4.w] : inp[i4.w];
        unsafeAtomicAdd(&acc[d4.x], wv.x * v0);
        unsafeAtomicAdd(&acc[d4.y], wv.y * v1);
        unsafeAtomicAdd(&acc[d4.z], wv.z * v2);
        unsafeAtomicAdd(&acc[d4.w], wv.w * v3);
    } else if (t == nq) {
        // scalar tail (E not divisible by 4)
        for (int e = nq * 4; e < E; ++e) {
            int m = bytemode ? (int)rmb[e] : ((const int*)rmb)[e];
            float v = m ? REFRACTORY * state[src[e]] : inp[input_idx[e]];
            unsafeAtomicAdd(&acc[dst[e]], w[e] * v);
        }
    }
}

// ---------------------------------------------------------------------------
// Kernel 3: activation + gather of the NOUT requested neurons.
// ---------------------------------------------------------------------------
__global__ void gather_out(const float* __restrict__ acc,
                           const int* __restrict__ act_id,
                           const int* __restrict__ out_ids,
                           float* __restrict__ out, int nout) {
    int i = blockIdx.x * blockDim.x + threadIdx.x;
    if (i >= nout) return;
    int n = out_ids[i];
    float x = acc[n];
    float y;
    switch (act_id[n]) {
        case 0: y = x; break;                                   // identity
        case 1: y = fmaxf(x, 0.0f); break;                      // relu
        case 2: y = x > 0.0f ? x : 0.01f * x; break;            // leaky_relu
        case 3: y = fminf(fmaxf(x, 0.0f), 1.0f); break;         // clipped_relu
        case 4: y = tanhf(x); break;                            // tanh
        case 5: y = 1.0f / (1.0f + expf(-x)); break;            // sigmoid
        case 6: y = fmaxf(x, 0.0f) + log1pf(expf(-fabsf(x))); break; // softplus
        default: y = fabsf(x); break;                           // abs
    }
    out[i] = y;
}

extern "C" void kernel_launch(void* const* d_in, const int* in_sizes, int n_in,
                              void* d_out, int out_size, void* d_ws, size_t ws_size,
                              hipStream_t stream) {
    const float* state     = (const float*)d_in[0];
    const float* weights   = (const float*)d_in[1];
    const float* biases    = (const float*)d_in[2];
    const float* inp       = (const float*)d_in[3];
    const int*   src       = (const int*)d_in[4];
    const int*   dst       = (const int*)d_in[5];
    const void*  rec_mask  = d_in[6];
    const int*   input_idx = (const int*)d_in[7];
    const int*   act_id    = (const int*)d_in[8];
    const int*   out_ids   = (const int*)d_in[9];
    float*       out       = (float*)d_out;

    const int N = in_sizes[0];
    const int E = in_sizes[1];
    const int NOUT = out_size;

    int*   flag = (int*)d_ws;
    float* acc  = (float*)((char*)d_ws + 256);  // N floats

    // 0) detect rec_mask storage mode (bool bytes vs int32)
    int nwords = E / 4;
    if (nwords > 16384) nwords = 16384;
    if (nwords < 1) nwords = 1;
    detect_mask<<<1, 256, 0, stream>>>((const unsigned int*)rec_mask, nwords, flag);

    // 1) init accumulator
    int initBlocks = (N + 1023) / 1024;
    if (initBlocks > 2048) initBlocks = 2048;
    init_acc<<<initBlocks, 256, 0, stream>>>(state, biases, acc, N);

    // 2) edge scatter (4 edges/thread + 1 tail thread)
    int nq = E / 4;
    int edgeBlocks = (nq + 1 + 255) / 256;
    edge_scatter<<<edgeBlocks, 256, 0, stream>>>(
        weights, src, dst, (const unsigned char*)rec_mask, input_idx,
        state, inp, acc, E, flag);

    // 3) activation + gather
    int outBlocks = (NOUT + 255) / 256;
    gather_out<<<outBlocks, 256, 0, stream>>>(acc, act_id, out_ids, out, NOUT);
}

// Round 2
// 103.612 us; speedup vs baseline: 7.7933x; 7.7933x over previous
//
#include <hip/hip_runtime.h>
#include <math.h>

#define REFRACTORY 0.33f

// ws layout: [0..4)=flag, [256..256+131072)=bitmap (1M bits), then acc (N floats)
#define WS_BITMAP_OFF 256
#define WS_ACC_OFF (256 + 131072)

// ---------------------------------------------------------------------------
// Kernel 0: detect whether rec_mask arrived as int32 (0/1 per dword) or as
// packed bool bytes (dword view gives values > 1). Writes flag to ws.
// ---------------------------------------------------------------------------
__global__ void detect_mask(const unsigned int* __restrict__ rm, int nwords,
                            int* __restrict__ flag) {
    __shared__ int s;
    if (threadIdx.x == 0) s = 0;
    __syncthreads();
    int found = 0;
    for (int i = threadIdx.x; i < nwords; i += blockDim.x)
        if (rm[i] > 1u) found = 1;
    if (found) atomicOr(&s, 1);
    __syncthreads();
    if (threadIdx.x == 0) *flag = s;
}

// ---------------------------------------------------------------------------
// Kernel 1: zero the membership bitmap (nwords32 = ceil(N/32))
// ---------------------------------------------------------------------------
__global__ void zero_bitmap(unsigned int* __restrict__ bm, int nwords) {
    int i = blockIdx.x * blockDim.x + threadIdx.x;
    int stride = gridDim.x * blockDim.x;
    for (; i < nwords; i += stride) bm[i] = 0u;
}

// ---------------------------------------------------------------------------
// Kernel 2: mark output neurons in the bitmap AND initialize their acc to
// prev + bias = REFRACTORY*state + bias. Duplicates in out_ids are benign
// (same value written, same bit set).
// ---------------------------------------------------------------------------
__global__ void mark_init(const int* __restrict__ out_ids,
                          const float* __restrict__ state,
                          const float* __restrict__ biases,
                          unsigned int* __restrict__ bm,
                          float* __restrict__ acc, int nout) {
    int i = blockIdx.x * blockDim.x + threadIdx.x;
    if (i >= nout) return;
    int n = out_ids[i];
    atomicOr(&bm[((unsigned)n) >> 5], 1u << (n & 31));
    acc[n] = REFRACTORY * state[n] + biases[n];
}

// ---------------------------------------------------------------------------
// Kernel 3: stream dst; for edges whose dst is an output neuron (~0.8%),
// do the full edge computation and atomically accumulate.
// ---------------------------------------------------------------------------
__device__ __forceinline__ void process_edge(
    int d, int e,
    const float* __restrict__ w, const int* __restrict__ src,
    const unsigned char* __restrict__ rmb, const int* __restrict__ input_idx,
    const float* __restrict__ state, const float* __restrict__ inp,
    float* __restrict__ acc, int bytemode) {
    int m = bytemode ? (int)rmb[e] : ((const int*)rmb)[e];
    float v = m ? REFRACTORY * state[src[e]] : inp[input_idx[e]];
    unsafeAtomicAdd(&acc[d], w[e] * v);
}

__global__ void edge_scan(const float* __restrict__ w,
                          const int* __restrict__ src,
                          const int* __restrict__ dst,
                          const unsigned char* __restrict__ rmb,
                          const int* __restrict__ input_idx,
                          const float* __restrict__ state,
                          const float* __restrict__ inp,
                          const unsigned int* __restrict__ bm,
                          float* __restrict__ acc, int E,
                          const int* __restrict__ flag) {
    int t = blockIdx.x * blockDim.x + threadIdx.x;
    int nq = E >> 2;
    if (t < nq) {
        int4 d4 = ((const int4*)dst)[t];
        unsigned int h0 = bm[((unsigned)d4.x) >> 5] & (1u << (d4.x & 31));
        unsigned int h1 = bm[((unsigned)d4.y) >> 5] & (1u << (d4.y & 31));
        unsigned int h2 = bm[((unsigned)d4.z) >> 5] & (1u << (d4.z & 31));
        unsigned int h3 = bm[((unsigned)d4.w) >> 5] & (1u << (d4.w & 31));
        if (h0 | h1 | h2 | h3) {
            const int bytemode = *flag;
            int e = t << 2;
            if (h0) process_edge(d4.x, e + 0, w, src, rmb, input_idx, state, inp, acc, bytemode);
            if (h1) process_edge(d4.y, e + 1, w, src, rmb, input_idx, state, inp, acc, bytemode);
            if (h2) process_edge(d4.z, e + 2, w, src, rmb, input_idx, state, inp, acc, bytemode);
            if (h3) process_edge(d4.w, e + 3, w, src, rmb, input_idx, state, inp, acc, bytemode);
        }
    } else if (t == nq) {
        const int bytemode = *flag;
        for (int e = nq * 4; e < E; ++e) {
            int d = dst[e];
            if (bm[((unsigned)d) >> 5] & (1u << (d & 31)))
                process_edge(d, e, w, src, rmb, input_idx, state, inp, acc, bytemode);
        }
    }
}

// ---------------------------------------------------------------------------
// Kernel 4: activation + gather of the NOUT requested neurons.
// ---------------------------------------------------------------------------
__global__ void gather_out(const float* __restrict__ acc,
                           const int* __restrict__ act_id,
                           const int* __restrict__ out_ids,
                           float* __restrict__ out, int nout) {
    int i = blockIdx.x * blockDim.x + threadIdx.x;
    if (i >= nout) return;
    int n = out_ids[i];
    float x = acc[n];
    float y;
    switch (act_id[n]) {
        case 0: y = x; break;                                   // identity
        case 1: y = fmaxf(x, 0.0f); break;                      // relu
        case 2: y = x > 0.0f ? x : 0.01f * x; break;            // leaky_relu
        case 3: y = fminf(fmaxf(x, 0.0f), 1.0f); break;         // clipped_relu
        case 4: y = tanhf(x); break;                            // tanh
        case 5: y = 1.0f / (1.0f + expf(-x)); break;            // sigmoid
        case 6: y = fmaxf(x, 0.0f) + log1pf(expf(-fabsf(x))); break; // softplus
        default: y = fabsf(x); break;                           // abs
    }
    out[i] = y;
}

extern "C" void kernel_launch(void* const* d_in, const int* in_sizes, int n_in,
                              void* d_out, int out_size, void* d_ws, size_t ws_size,
                              hipStream_t stream) {
    const float* state     = (const float*)d_in[0];
    const float* weights   = (const float*)d_in[1];
    const float* biases    = (const float*)d_in[2];
    const float* inp       = (const float*)d_in[3];
    const int*   src       = (const int*)d_in[4];
    const int*   dst       = (const int*)d_in[5];
    const void*  rec_mask  = d_in[6];
    const int*   input_idx = (const int*)d_in[7];
    const int*   act_id    = (const int*)d_in[8];
    const int*   out_ids   = (const int*)d_in[9];
    float*       out       = (float*)d_out;

    const int N = in_sizes[0];
    const int E = in_sizes[1];
    const int NOUT = out_size;

    int*          flag = (int*)d_ws;
    unsigned int* bm   = (unsigned int*)((char*)d_ws + WS_BITMAP_OFF);
    float*        acc  = (float*)((char*)d_ws + WS_ACC_OFF);

    const int bmWords = (N + 31) / 32;

    // 0) detect rec_mask storage mode
    int nwords = E / 4;
    if (nwords > 16384) nwords = 16384;
    if (nwords < 1) nwords = 1;
    detect_mask<<<1, 256, 0, stream>>>((const unsigned int*)rec_mask, nwords, flag);

    // 1) zero bitmap
    int zb = (bmWords + 1023) / 1024;
    if (zb > 128) zb = 128;
    zero_bitmap<<<zb, 256, 0, stream>>>(bm, bmWords);

    // 2) mark output neurons + init their accumulators
    mark_init<<<(NOUT + 255) / 256, 256, 0, stream>>>(out_ids, state, biases, bm, acc, NOUT);

    // 3) stream dst, process only edges targeting output neurons
    int nq = E / 4;
    int edgeBlocks = (nq + 1 + 255) / 256;
    edge_scan<<<edgeBlocks, 256, 0, stream>>>(
        weights, src, dst, (const unsigned char*)rec_mask, input_idx,
        state, inp, bm, acc, E, flag);

    // 4) activation + gather
    gather_out<<<(NOUT + 255) / 256, 256, 0, stream>>>(acc, act_id, out_ids, out, NOUT);
}

// Round 3
// 100.851 us; speedup vs baseline: 8.0067x; 1.0274x over previous
//
#include <hip/hip_runtime.h>
#include <math.h>

#define REFRACTORY 0.33f
#define FILT_WORDS 16384  // 64 KB coarse filter: 524288 bits

// ws layout:
//   [0,4)                      flag (rec_mask byte-mode)
//   [256, 256+64K)             coarse filter (global copy)
//   [256+64K, 256+64K+128K)    exact bitmap (1M bits)
//   [256+192K, ...)            acc (N floats)
#define WS_GFILT_OFF 256
#define WS_BM_OFF    (256 + 65536)
#define WS_ACC_OFF   (256 + 65536 + 131072)

// ---------------------------------------------------------------------------
// Kernel 0: zero both filters; block 0 additionally detects rec_mask mode
// (int32 0/1 per dword vs packed bool bytes -> dword values > 1).
// ---------------------------------------------------------------------------
__global__ void prep(const unsigned int* __restrict__ rm, int nwords,
                     int* __restrict__ flag,
                     unsigned int* __restrict__ gfilt,
                     unsigned int* __restrict__ bm, int bmWords) {
    int gid = blockIdx.x * blockDim.x + threadIdx.x;
    int stride = gridDim.x * blockDim.x;
    for (int i = gid; i < FILT_WORDS; i += stride) gfilt[i] = 0u;
    for (int i = gid; i < bmWords; i += stride) bm[i] = 0u;
    if (blockIdx.x == 0) {
        __shared__ int s;
        if (threadIdx.x == 0) s = 0;
        __syncthreads();
        int found = 0;
        for (int i = threadIdx.x; i < nwords; i += blockDim.x)
            if (rm[i] > 1u) found = 1;
        if (found) atomicOr(&s, 1);
        __syncthreads();
        if (threadIdx.x == 0) *flag = s;
    }
}

// ---------------------------------------------------------------------------
// Kernel 1: mark output neurons (coarse + exact) and init their accumulators.
// ---------------------------------------------------------------------------
__global__ void mark_init(const int* __restrict__ out_ids,
                          const float* __restrict__ state,
                          const float* __restrict__ biases,
                          unsigned int* __restrict__ gfilt,
                          unsigned int* __restrict__ bm,
                          float* __restrict__ acc, int nout, int shift) {
    int i = blockIdx.x * blockDim.x + threadIdx.x;
    if (i >= nout) return;
    int n = out_ids[i];
    atomicOr(&bm[((unsigned)n) >> 5], 1u << (n & 31));
    unsigned g = ((unsigned)n) >> shift;
    atomicOr(&gfilt[g >> 5], 1u << (g & 31));
    acc[n] = REFRACTORY * state[n] + biases[n];
}

// ---------------------------------------------------------------------------
// Kernel 2: stream dst; LDS coarse filter probe (1.56% pass) -> exact global
// bitmap check -> full edge processing for true hits (~0.8%).
// ---------------------------------------------------------------------------
__device__ __forceinline__ void process_edge(
    int d, int e,
    const float* __restrict__ w, const int* __restrict__ src,
    const unsigned char* __restrict__ rmb, const int* __restrict__ input_idx,
    const float* __restrict__ state, const float* __restrict__ inp,
    float* __restrict__ acc, int bytemode) {
    int m = bytemode ? (int)rmb[e] : ((const int*)rmb)[e];
    float v = m ? REFRACTORY * state[src[e]] : inp[input_idx[e]];
    unsafeAtomicAdd(&acc[d], w[e] * v);
}

__global__ void __launch_bounds__(512)
edge_scan(const float* __restrict__ w,
          const int* __restrict__ src,
          const int* __restrict__ dst,
          const unsigned char* __restrict__ rmb,
          const int* __restrict__ input_idx,
          const float* __restrict__ state,
          const float* __restrict__ inp,
          const unsigned int* __restrict__ gfilt,
          const unsigned int* __restrict__ bm,
          float* __restrict__ acc, int E,
          const int* __restrict__ flag, int shift) {
    __shared__ unsigned int filt[FILT_WORDS];
    // stage coarse filter into LDS (16B/lane)
    {
        const uint4* g4 = (const uint4*)gfilt;
        uint4* f4 = (uint4*)filt;
        for (int i = threadIdx.x; i < FILT_WORDS / 4; i += blockDim.x)
            f4[i] = g4[i];
    }
    __syncthreads();
    const int bytemode = *flag;
    const int sh5 = shift + 5;
    int tid = blockIdx.x * blockDim.x + threadIdx.x;
    int stride = gridDim.x * blockDim.x;
    int nq = E >> 2;
    for (int t = tid; t < nq; t += stride) {
        int4 d4 = ((const int4*)dst)[t];
        unsigned c0 = filt[((unsigned)d4.x) >> sh5] & (1u << ((((unsigned)d4.x) >> shift) & 31));
        unsigned c1 = filt[((unsigned)d4.y) >> sh5] & (1u << ((((unsigned)d4.y) >> shift) & 31));
        unsigned c2 = filt[((unsigned)d4.z) >> sh5] & (1u << ((((unsigned)d4.z) >> shift) & 31));
        unsigned c3 = filt[((unsigned)d4.w) >> sh5] & (1u << ((((unsigned)d4.w) >> shift) & 31));
        if (c0 | c1 | c2 | c3) {
            int e = t << 2;
            if (c0 && (bm[((unsigned)d4.x) >> 5] & (1u << (d4.x & 31))))
                process_edge(d4.x, e + 0, w, src, rmb, input_idx, state, inp, acc, bytemode);
            if (c1 && (bm[((unsigned)d4.y) >> 5] & (1u << (d4.y & 31))))
                process_edge(d4.y, e + 1, w, src, rmb, input_idx, state, inp, acc, bytemode);
            if (c2 && (bm[((unsigned)d4.z) >> 5] & (1u << (d4.z & 31))))
                process_edge(d4.z, e + 2, w, src, rmb, input_idx, state, inp, acc, bytemode);
            if (c3 && (bm[((unsigned)d4.w) >> 5] & (1u << (d4.w & 31))))
                process_edge(d4.w, e + 3, w, src, rmb, input_idx, state, inp, acc, bytemode);
        }
    }
    // tail (E not divisible by 4)
    int rem = E - nq * 4;
    if (tid < rem) {
        int e = nq * 4 + tid;
        int d = dst[e];
        if (bm[((unsigned)d) >> 5] & (1u << (d & 31)))
            process_edge(d, e, w, src, rmb, input_idx, state, inp, acc, bytemode);
    }
}

// ---------------------------------------------------------------------------
// Kernel 3: activation + gather of the NOUT requested neurons.
// ---------------------------------------------------------------------------
__global__ void gather_out(const float* __restrict__ acc,
                           const int* __restrict__ act_id,
                           const int* __restrict__ out_ids,
                           float* __restrict__ out, int nout) {
    int i = blockIdx.x * blockDim.x + threadIdx.x;
    if (i >= nout) return;
    int n = out_ids[i];
    float x = acc[n];
    float y;
    switch (act_id[n]) {
        case 0: y = x; break;                                   // identity
        case 1: y = fmaxf(x, 0.0f); break;                      // relu
        case 2: y = x > 0.0f ? x : 0.01f * x; break;            // leaky_relu
        case 3: y = fminf(fmaxf(x, 0.0f), 1.0f); break;         // clipped_relu
        case 4: y = tanhf(x); break;                            // tanh
        case 5: y = 1.0f / (1.0f + expf(-x)); break;            // sigmoid
        case 6: y = fmaxf(x, 0.0f) + log1pf(expf(-fabsf(x))); break; // softplus
        default: y = fabsf(x); break;                           // abs
    }
    out[i] = y;
}

extern "C" void kernel_launch(void* const* d_in, const int* in_sizes, int n_in,
                              void* d_out, int out_size, void* d_ws, size_t ws_size,
                              hipStream_t stream) {
    const float* state     = (const float*)d_in[0];
    const float* weights   = (const float*)d_in[1];
    const float* biases    = (const float*)d_in[2];
    const float* inp       = (const float*)d_in[3];
    const int*   src       = (const int*)d_in[4];
    const int*   dst       = (const int*)d_in[5];
    const void*  rec_mask  = d_in[6];
    const int*   input_idx = (const int*)d_in[7];
    const int*   act_id    = (const int*)d_in[8];
    const int*   out_ids   = (const int*)d_in[9];
    float*       out       = (float*)d_out;

    const int N = in_sizes[0];
    const int E = in_sizes[1];
    const int NOUT = out_size;

    int*          flag  = (int*)d_ws;
    unsigned int* gfilt = (unsigned int*)((char*)d_ws + WS_GFILT_OFF);
    unsigned int* bm    = (unsigned int*)((char*)d_ws + WS_BM_OFF);
    float*        acc   = (float*)((char*)d_ws + WS_ACC_OFF);

    const int bmWords = (N + 31) / 32;

    // coarse shift: bits = ceil(N >> shift) must fit 524288 filter bits
    int shift = 0;
    while ((((long long)N + ((1LL << shift) - 1)) >> shift) > (long long)FILT_WORDS * 32)
        shift++;

    // 0) zero filters + detect rec_mask mode
    int nwords = E / 4;
    if (nwords > 16384) nwords = 16384;
    if (nwords < 1) nwords = 1;
    prep<<<64, 256, 0, stream>>>((const unsigned int*)rec_mask, nwords, flag,
                                 gfilt, bm, bmWords);

    // 1) mark output neurons + init their accumulators
    mark_init<<<(NOUT + 255) / 256, 256, 0, stream>>>(out_ids, state, biases,
                                                      gfilt, bm, acc, NOUT, shift);

    // 2) stream dst with LDS coarse filter
    edge_scan<<<512, 512, 0, stream>>>(
        weights, src, dst, (const unsigned char*)rec_mask, input_idx,
        state, inp, gfilt, bm, acc, E, flag, shift);

    // 3) activation + gather
    gather_out<<<(NOUT + 255) / 256, 256, 0, stream>>>(acc, act_id, out_ids, out, NOUT);
}

// Round 4
// 78.507 us; speedup vs baseline: 10.2854x; 1.2846x over previous
//
#include <hip/hip_runtime.h>
#include <math.h>

#define REFRACTORY 0.33f
#define FILT_WORDS 8192      // 32 KB LDS coarse filter: 262144 bits
#define QCAP 1792            // per-block LDS queue entries (7 KB)
#define QMAX_DEFAULT (2*1024*1024)

// ws layout:
//   [0,4)    flag (rec_mask byte-mode)
//   [4,8)    qcount
//   [256, +32K)   gfilt (global copy of coarse filter)
//   [+32K, +128K) bm (exact 1-bit-per-neuron bitmap)
//   then acc (N floats), then qbuf (candidate edge indices)
#define WS_GFILT_OFF 256
#define WS_BM_OFF    (WS_GFILT_OFF + FILT_WORDS * 4)
#define WS_ACC_OFF   (WS_BM_OFF + 131072)

// ---------------------------------------------------------------------------
// Kernel 0: zero filters + qcount; block 0 detects rec_mask storage mode.
// ---------------------------------------------------------------------------
__global__ void prep(const unsigned int* __restrict__ rm, int nwords,
                     int* __restrict__ flag, int* __restrict__ qcount,
                     unsigned int* __restrict__ gfilt,
                     unsigned int* __restrict__ bm, int bmWords) {
    int gid = blockIdx.x * blockDim.x + threadIdx.x;
    int stride = gridDim.x * blockDim.x;
    for (int i = gid; i < FILT_WORDS; i += stride) gfilt[i] = 0u;
    for (int i = gid; i < bmWords; i += stride) bm[i] = 0u;
    if (gid == 0) *qcount = 0;
    if (blockIdx.x == 0) {
        __shared__ int s;
        if (threadIdx.x == 0) s = 0;
        __syncthreads();
        int found = 0;
        for (int i = threadIdx.x; i < nwords; i += blockDim.x)
            if (rm[i] > 1u) found = 1;
        if (found) atomicOr(&s, 1);
        __syncthreads();
        if (threadIdx.x == 0) *flag = s;
    }
}

// ---------------------------------------------------------------------------
// Kernel 1: mark output neurons (coarse + exact) and init their accumulators.
// ---------------------------------------------------------------------------
__global__ void mark_init(const int* __restrict__ out_ids,
                          const float* __restrict__ state,
                          const float* __restrict__ biases,
                          unsigned int* __restrict__ gfilt,
                          unsigned int* __restrict__ bm,
                          float* __restrict__ acc, int nout, int shift) {
    int i = blockIdx.x * blockDim.x + threadIdx.x;
    if (i >= nout) return;
    int n = out_ids[i];
    atomicOr(&bm[((unsigned)n) >> 5], 1u << (n & 31));
    unsigned g = ((unsigned)n) >> shift;
    atomicOr(&gfilt[g >> 5], 1u << (g & 31));
    acc[n] = REFRACTORY * state[n] + biases[n];
}

// ---------------------------------------------------------------------------
// Full edge processing (used by phase B and rare fallback paths).
// ---------------------------------------------------------------------------
__device__ __forceinline__ void process_edge(
    int d, int e,
    const float* __restrict__ w, const int* __restrict__ src,
    const unsigned char* __restrict__ rmb, const int* __restrict__ input_idx,
    const float* __restrict__ state, const float* __restrict__ inp,
    float* __restrict__ acc, int bytemode) {
    int m = bytemode ? (int)rmb[e] : ((const int*)rmb)[e];
    float v = m ? REFRACTORY * state[src[e]] : inp[input_idx[e]];
    unsafeAtomicAdd(&acc[d], w[e] * v);
}

// ---------------------------------------------------------------------------
// Kernel 2 (phase A): stream dst, probe LDS coarse filter, enqueue candidate
// edge indices into a block-local LDS queue; flush once per block.
// NO scattered loads in the streaming loop.
// ---------------------------------------------------------------------------
__global__ void __launch_bounds__(256, 4)
edge_compact(const int* __restrict__ dst,
             const unsigned int* __restrict__ gfilt,
             int E, int shift,
             int* __restrict__ qbuf, int* __restrict__ qcount, int qmax,
             const float* __restrict__ w, const int* __restrict__ src,
             const unsigned char* __restrict__ rmb,
             const int* __restrict__ input_idx,
             const float* __restrict__ state, const float* __restrict__ inp,
             const unsigned int* __restrict__ bm, float* __restrict__ acc,
             const int* __restrict__ flag) {
    __shared__ unsigned int filt[FILT_WORDS];
    __shared__ int lq[QCAP];
    __shared__ int lcnt, lbase;
    // stage coarse filter into LDS
    {
        const uint4* g4 = (const uint4*)gfilt;
        uint4* f4 = (uint4*)filt;
        for (int i = threadIdx.x; i < FILT_WORDS / 4; i += blockDim.x)
            f4[i] = g4[i];
    }
    if (threadIdx.x == 0) lcnt = 0;
    __syncthreads();

    const int sh5 = shift + 5;
    int gtid = blockIdx.x * blockDim.x + threadIdx.x;
    int gstride = gridDim.x * blockDim.x;
    int nq = E >> 2;
    const int4* d4p = (const int4*)dst;

#define SLOT(dv, ev, valid)                                                    \
    {                                                                          \
        unsigned dd = (unsigned)(dv);                                          \
        bool c = (valid) && ((filt[dd >> sh5] >> ((dd >> shift) & 31)) & 1u);  \
        if (c) {                                                               \
            int off = atomicAdd(&lcnt, 1);                                     \
            if (off < QCAP) lq[off] = (ev);                                    \
            else if ((bm[dd >> 5] >> (dd & 31)) & 1u)                          \
                process_edge((int)dd, (ev), w, src, rmb, input_idx,            \
                             state, inp, acc, *flag);                          \
        }                                                                      \
    }

    for (int t = gtid; t < nq; t += 2 * gstride) {
        int4 A = d4p[t];
        int t2 = t + gstride;
        bool has2 = (t2 < nq);
        int4 B = has2 ? d4p[t2] : make_int4(0, 0, 0, 0);
        int ea = t << 2;
        SLOT(A.x, ea + 0, true);
        SLOT(A.y, ea + 1, true);
        SLOT(A.z, ea + 2, true);
        SLOT(A.w, ea + 3, true);
        int eb = t2 << 2;
        SLOT(B.x, eb + 0, has2);
        SLOT(B.y, eb + 1, has2);
        SLOT(B.z, eb + 2, has2);
        SLOT(B.w, eb + 3, has2);
    }
#undef SLOT

    // tail edges (E not divisible by 4): exact check + inline process
    int rem = E - nq * 4;
    if (gtid < rem) {
        int e = nq * 4 + gtid;
        unsigned d = (unsigned)dst[e];
        if ((bm[d >> 5] >> (d & 31)) & 1u)
            process_edge((int)d, e, w, src, rmb, input_idx, state, inp, acc, *flag);
    }

    // block flush
    __syncthreads();
    int n = lcnt < QCAP ? lcnt : QCAP;
    if (threadIdx.x == 0) lbase = atomicAdd(qcount, n);
    __syncthreads();
    int base = lbase;
    for (int i = threadIdx.x; i < n; i += blockDim.x) {
        int gi = base + i;
        if (gi < qmax) qbuf[gi] = lq[i];
        else {  // global queue overflow: process inline (rare/never)
            int e = lq[i];
            unsigned d = (unsigned)dst[e];
            if ((bm[d >> 5] >> (d & 31)) & 1u)
                process_edge((int)d, e, w, src, rmb, input_idx, state, inp, acc, *flag);
        }
    }
}

// ---------------------------------------------------------------------------
// Kernel 3 (phase B): process compacted candidates; one lane per edge.
// ---------------------------------------------------------------------------
__global__ void __launch_bounds__(256)
process_candidates(const int* __restrict__ qbuf, const int* __restrict__ qcount,
                   int qmax,
                   const int* __restrict__ dst,
                   const float* __restrict__ w, const int* __restrict__ src,
                   const unsigned char* __restrict__ rmb,
                   const int* __restrict__ input_idx,
                   const float* __restrict__ state, const float* __restrict__ inp,
                   const unsigned int* __restrict__ bm, float* __restrict__ acc,
                   const int* __restrict__ flag) {
    int total = *qcount;
    if (total > qmax) total = qmax;
    const int bytemode = *flag;
    int i = blockIdx.x * blockDim.x + threadIdx.x;
    int stride = gridDim.x * blockDim.x;
    for (; i < total; i += stride) {
        int e = qbuf[i];
        unsigned d = (unsigned)dst[e];
        if ((bm[d >> 5] >> (d & 31)) & 1u)
            process_edge((int)d, e, w, src, rmb, input_idx, state, inp, acc, bytemode);
    }
}

// ---------------------------------------------------------------------------
// Kernel 4: activation + gather of the NOUT requested neurons.
// ---------------------------------------------------------------------------
__global__ void gather_out(const float* __restrict__ acc,
                           const int* __restrict__ act_id,
                           const int* __restrict__ out_ids,
                           float* __restrict__ out, int nout) {
    int i = blockIdx.x * blockDim.x + threadIdx.x;
    if (i >= nout) return;
    int n = out_ids[i];
    float x = acc[n];
    float y;
    switch (act_id[n]) {
        case 0: y = x; break;                                   // identity
        case 1: y = fmaxf(x, 0.0f); break;                      // relu
        case 2: y = x > 0.0f ? x : 0.01f * x; break;            // leaky_relu
        case 3: y = fminf(fmaxf(x, 0.0f), 1.0f); break;         // clipped_relu
        case 4: y = tanhf(x); break;                            // tanh
        case 5: y = 1.0f / (1.0f + expf(-x)); break;            // sigmoid
        case 6: y = fmaxf(x, 0.0f) + log1pf(expf(-fabsf(x))); break; // softplus
        default: y = fabsf(x); break;                           // abs
    }
    out[i] = y;
}

extern "C" void kernel_launch(void* const* d_in, const int* in_sizes, int n_in,
                              void* d_out, int out_size, void* d_ws, size_t ws_size,
                              hipStream_t stream) {
    const float* state     = (const float*)d_in[0];
    const float* weights   = (const float*)d_in[1];
    const float* biases    = (const float*)d_in[2];
    const float* inp       = (const float*)d_in[3];
    const int*   src       = (const int*)d_in[4];
    const int*   dst       = (const int*)d_in[5];
    const void*  rec_mask  = d_in[6];
    const int*   input_idx = (const int*)d_in[7];
    const int*   act_id    = (const int*)d_in[8];
    const int*   out_ids   = (const int*)d_in[9];
    float*       out       = (float*)d_out;

    const int N = in_sizes[0];
    const int E = in_sizes[1];
    const int NOUT = out_size;

    int*          flag   = (int*)d_ws;
    int*          qcount = (int*)((char*)d_ws + 4);
    unsigned int* gfilt  = (unsigned int*)((char*)d_ws + WS_GFILT_OFF);
    unsigned int* bm     = (unsigned int*)((char*)d_ws + WS_BM_OFF);
    float*        acc    = (float*)((char*)d_ws + WS_ACC_OFF);

    size_t qoff = (size_t)WS_ACC_OFF + (size_t)N * 4;
    qoff = (qoff + 255) & ~(size_t)255;
    int* qbuf = (int*)((char*)d_ws + qoff);
    long long avail = (long long)ws_size - (long long)qoff;
    int qmax = 0;
    if (avail > 0) {
        long long q = avail / 4;
        qmax = (int)(q < (long long)QMAX_DEFAULT ? q : (long long)QMAX_DEFAULT);
    }

    const int bmWords = (N + 31) / 32;

    // coarse shift: ceil(N >> shift) must fit FILT_WORDS*32 bits
    int shift = 0;
    while ((((long long)N + ((1LL << shift) - 1)) >> shift) > (long long)FILT_WORDS * 32)
        shift++;

    // 0) zero filters + qcount, detect rec_mask mode
    int nwords = E / 4;
    if (nwords > 16384) nwords = 16384;
    if (nwords < 1) nwords = 1;
    prep<<<64, 256, 0, stream>>>((const unsigned int*)rec_mask, nwords,
                                 flag, qcount, gfilt, bm, bmWords);

    // 1) mark output neurons + init their accumulators
    mark_init<<<(NOUT + 255) / 256, 256, 0, stream>>>(out_ids, state, biases,
                                                      gfilt, bm, acc, NOUT, shift);

    // 2) phase A: stream dst, compact candidate edges
    edge_compact<<<1024, 256, 0, stream>>>(
        dst, gfilt, E, shift, qbuf, qcount, qmax,
        weights, src, (const unsigned char*)rec_mask, input_idx,
        state, inp, bm, acc, flag);

    // 3) phase B: process candidates (exact bm check inside)
    process_candidates<<<2048, 256, 0, stream>>>(
        qbuf, qcount, qmax, dst,
        weights, src, (const unsigned char*)rec_mask, input_idx,
        state, inp, bm, acc, flag);

    // 4) activation + gather
    gather_out<<<(NOUT + 255) / 256, 256, 0, stream>>>(acc, act_id, out_ids, out, NOUT);
}